// Round 8
// baseline (103.084 us; speedup 1.0000x reference)
//
#include <hip/hip_runtime.h>
#include <hip/hip_bf16.h>

#define NB 8
#define NN 2048
#define NF 64      // in features
#define NP 64      // out features per head
#define NH 4
#define NHF 256    // NH*NP
#define LOG2E 1.4426950408889634f

typedef float f32x4 __attribute__((ext_vector_type(4)));
typedef short bf16x8 __attribute__((ext_vector_type(8)));
typedef short s16x4 __attribute__((ext_vector_type(4)));

// f32 -> bf16 bits, round-nearest-even
__device__ __forceinline__ short f2bf(float f) {
    unsigned u = __builtin_bit_cast(unsigned, f);
    unsigned r = (u + 0x7fffu + ((u >> 16) & 1u)) >> 16;
    return (short)r;
}

__device__ __forceinline__ float exp2_fast(float x) {
#if __has_builtin(__builtin_amdgcn_exp2f)
    return __builtin_amdgcn_exp2f(x);
#else
    float r;
    asm volatile("v_exp_f32 %0, %1\n\ts_nop 1" : "=v"(r) : "v"(x));
    return r;
#endif
}

__device__ __forceinline__ void async16(const void* g, void* l) {
    __builtin_amdgcn_global_load_lds(
        (const __attribute__((address_space(1))) void*)g,
        (__attribute__((address_space(3))) void*)l, 16, 0, 0);
}

// Full drain before barrier: the compiler's implicit wait before s_barrier may
// be a COUNTED vmcnt targeting only VGPR loads, leaving LDS-DMA (global_load_lds)
// outstanding across the barrier -> replay-timing race (R7 post-timing NaN).
#define DRAIN_BARRIER() do {                                                  \
        asm volatile("s_waitcnt vmcnt(0) lgkmcnt(0)" ::: "memory");           \
        __syncthreads();                                                      \
    } while (0)

// ---------------------------------------------------------------------------
// Kernel A1: s_out[b,h,n] = (x[b,n,:] . (W[h] @ a_out[h])) * LOG2E  (prescaled
// for the exp2-domain softmax in gat_attn), same for s_in.
// ---------------------------------------------------------------------------
__global__ __launch_bounds__(256) void gat_scores(
    const float* __restrict__ x, const float* __restrict__ W,
    const float* __restrict__ a_out, const float* __restrict__ a_in,
    float* __restrict__ s_out, float* __restrict__ s_in)
{
    __shared__ float co_lds[NH][NF];
    __shared__ float ci_lds[NH][NF];
    int tid = threadIdx.x;
    int h = tid >> 6, f = tid & 63;
    {
        float co = 0.f, ci = 0.f;
        const float* wrow = W + (h * NF + f) * NP;
        #pragma unroll 8
        for (int o = 0; o < NP; ++o) {
            float w = wrow[o];
            co = fmaf(w, a_out[h * NP + o], co);
            ci = fmaf(w, a_in[h * NP + o], ci);
        }
        co_lds[h][f] = co;
        ci_lds[h][f] = ci;
    }
    __syncthreads();
    int wid = tid >> 6, lane = tid & 63;
    float cov[NH], civ[NH];
    #pragma unroll
    for (int hh = 0; hh < NH; ++hh) { cov[hh] = co_lds[hh][lane]; civ[hh] = ci_lds[hh][lane]; }
    int base = blockIdx.x * 64 + wid * 16;     // global row in [0, B*N)
    for (int r = 0; r < 16; ++r) {
        int gn = base + r;
        float xv = x[(size_t)gn * NF + lane];
        #pragma unroll
        for (int hh = 0; hh < NH; ++hh) {
            float vo = xv * cov[hh];
            float vi = xv * civ[hh];
            #pragma unroll
            for (int s2 = 1; s2 < 64; s2 <<= 1) {
                vo += __shfl_xor(vo, s2, 64);
                vi += __shfl_xor(vi, s2, 64);
            }
            if (lane == 0) {
                int b = gn >> 11, n = gn & (NN - 1);
                s_out[((size_t)b * NH + hh) * NN + n] = vo * LOG2E;
                s_in [((size_t)b * NH + hh) * NN + n] = vi * LOG2E;
            }
        }
    }
}

// ---------------------------------------------------------------------------
// Kernel A2: featsT interleaved: element (feature o, node j) of head (b,h) at
// base(b,h) + (j>>3)*512 + o*8 + (j&7)  => V-frag loads are 256B-contiguous.
// ---------------------------------------------------------------------------
__global__ __launch_bounds__(256) void gat_feats(
    const float* __restrict__ x, const float* __restrict__ W,
    short* __restrict__ featsT)
{
    int blk = blockIdx.x;
    int nb = blk & 31;           // N/64 = 32
    int h  = (blk >> 5) & 3;
    int b  = blk >> 7;
    int tid = threadIdx.x, wid = tid >> 6, lane = tid & 63;
    int n0 = nb * 64 + wid * 16;
    int rA = lane & 15, g = lane >> 4;

    bf16x8 af[2];
    #pragma unroll
    for (int kk = 0; kk < 2; ++kk) {
        const float* xp = x + ((size_t)(b * NN) + n0 + rA) * NF + kk * 32 + g * 8;
        f32x4 x0 = *(const f32x4*)xp;
        f32x4 x1 = *(const f32x4*)(xp + 4);
        #pragma unroll
        for (int e = 0; e < 4; ++e) {
            af[kk][e]     = f2bf(x0[e]);
            af[kk][e + 4] = f2bf(x1[e]);
        }
    }
    f32x4 acc[4] = {};
    #pragma unroll
    for (int o = 0; o < 4; ++o) {
        #pragma unroll
        for (int kk = 0; kk < 2; ++kk) {
            bf16x8 bfv;
            #pragma unroll
            for (int e = 0; e < 8; ++e) {
                float wv = W[((size_t)h * NF + kk * 32 + g * 8 + e) * NP + o * 16 + rA];
                bfv[e] = f2bf(wv);
            }
            acc[o] = __builtin_amdgcn_mfma_f32_16x16x32_bf16(af[kk], bfv, acc[o], 0, 0, 0);
        }
    }
    size_t hb = (size_t)(b * NH + h) * NP * NN;
    int jq = n0 / 8 + (g >> 1);     // j>>3 for j = n0 + g*4
    int jr = (g & 1) * 4;           // j&7
    #pragma unroll
    for (int o = 0; o < 4; ++o) {
        s16x4 pk;
        pk[0] = f2bf(acc[o][0]);
        pk[1] = f2bf(acc[o][1]);
        pk[2] = f2bf(acc[o][2]);
        pk[3] = f2bf(acc[o][3]);
        *(s16x4*)(featsT + hb + (size_t)jq * 512 + (o * 16 + rA) * 8 + jr) = pk;
    }
}

// ---------------------------------------------------------------------------
// Kernel B: fused masked-softmax attention + PV.
// Grid: B*(N/16) = 1024 blocks x 256 thr (4 waves = 4 heads, 16 i-rows).
// Super-chunk = 256 j per barrier (8 iterations). adj double-buffered in LDS.
// Staging: one async16 = one full 1024B LDS row at wave-uniform dest (HW puts
// lane L at +L*16, m104); swizzle on the per-lane GLOBAL source (lane L reads
// block L ^ (row&7)). Read: frag block (jg*2+c) ^ (r&7) within 128B groups.
// exp2-domain P; denominator via 5th MFMA against all-ones B.
// Explicit vmcnt drain before every barrier (replay-race fix, R7).
// ---------------------------------------------------------------------------
__global__ __launch_bounds__(256)
__attribute__((amdgpu_waves_per_eu(4, 4)))
void gat_attn(
    const float* __restrict__ adj,     // [B,N,N]
    const short* __restrict__ featsT,  // interleaved, see gat_feats
    const float* __restrict__ s_out,   // [B,H,N]  (prescaled by log2e)
    const float* __restrict__ s_in,    // [B,H,N]  (prescaled by log2e)
    const float* __restrict__ biases,  // [H,FP]
    float* __restrict__ out)           // [B,N,H*FP]
{
    __shared__ __align__(16) float adj_lds[2][4096];  // 2 x 16 KB (16 rows x 256 j)

    int blk = blockIdx.x;
    int b  = blk >> 7;            // 128 i-tiles per batch
    int it = blk & 127;
    int i0 = it * 16;
    int tid = threadIdx.x;
    int h = tid >> 6;             // wave = head (wave-uniform)
    int lane = tid & 63;
    int r  = lane & 15;           // A-frag row / B-frag col
    int jg = lane >> 4;

    // per-lane global source for the 4 rows this wave stages (row = h*4+k):
    // lane L fetches 16B block (L ^ (row&7)) of the row's 1024B super-chunk.
    const char* asrc[4];
    #pragma unroll
    for (int k = 0; k < 4; ++k) {
        int row = h * 4 + k;
        asrc[k] = (const char*)(adj + ((size_t)b * NN + i0 + row) * NN)
                  + ((lane ^ (row & 7)) << 4);
    }

#define STAGE(BUF, SC) do {                                                   \
        _Pragma("unroll")                                                     \
        for (int k = 0; k < 4; ++k)                                           \
            async16(asrc[k] + (size_t)(SC) * 1024,                            \
                    &adj_lds[BUF][(h * 4 + k) << 8]);                         \
    } while (0)

    // prologue: stage super-chunk 0 into buf 0
    STAGE(0, 0);

    float so = s_out[((size_t)b * NH + h) * NN + i0 + r];
    const float* sirow = s_in + ((size_t)b * NH + h) * NN + jg * 8;
    const short* vwave = featsT + (size_t)(b * NH + h) * NP * NN + jg * 512 + r * 8;
    int rsw = r & 7;
    int f0 = ((jg * 2)     ^ rsw) << 2;   // float offset of frag half 0 in 128B group
    int f1 = ((jg * 2 + 1) ^ rsw) << 2;   // float offset of frag half 1
    int rbase = r << 8;                   // row stride = 256 floats (1KB)

    float bias_v[4];
    #pragma unroll
    for (int o = 0; o < 4; ++o) bias_v[o] = biases[h * NP + o * 16 + r];

    bf16x8 ones;
    #pragma unroll
    for (int e = 0; e < 8; ++e) ones[e] = (short)0x3F80;   // bf16 1.0

    DRAIN_BARRIER();   // prologue stage fully landed in LDS

    f32x4 acc[4] = {};
    f32x4 acc4 = {};   // row-sum accumulator (denominator)

// one 16x32 P-subtile: 2 LDS adj reads + P-compute + 5 MFMA
#define KSTEP(S, KS, Q0, Q1, V0, V1, V2, V3) do {                             \
        const float* ap = ab + rbase + (((S) * 16 + (KS) * 8) << 2);          \
        f32x4 a0 = *(const f32x4*)(ap + f0);                                  \
        f32x4 a1 = *(const f32x4*)(ap + f1);                                  \
        bf16x8 af;                                                            \
        _Pragma("unroll")                                                     \
        for (int e = 0; e < 8; ++e) {                                         \
            float av = (e < 4) ? a0[e] : a1[e - 4];                           \
            float sv = (e < 4) ? Q0[e] : Q1[e - 4];                           \
            float t = so + sv;                                                \
            float lr = fmaxf(t, 0.2f * t);                                    \
            float arg = fmaf(av, LOG2E, lr);                                  \
            float pe_ = exp2_fast(arg);                                       \
            float p = (av != 0.f) ? pe_ : 0.f;                                \
            __hip_bfloat16 hbv = __float2bfloat16(p);                         \
            af[e] = (short)__builtin_bit_cast(unsigned short, hbv);           \
        }                                                                     \
        acc[0] = __builtin_amdgcn_mfma_f32_16x16x32_bf16(af, V0, acc[0], 0, 0, 0); \
        acc[1] = __builtin_amdgcn_mfma_f32_16x16x32_bf16(af, V1, acc[1], 0, 0, 0); \
        acc[2] = __builtin_amdgcn_mfma_f32_16x16x32_bf16(af, V2, acc[2], 0, 0, 0); \
        acc[3] = __builtin_amdgcn_mfma_f32_16x16x32_bf16(af, V3, acc[3], 0, 0, 0); \
        acc4   = __builtin_amdgcn_mfma_f32_16x16x32_bf16(af, ones, acc4, 0, 0, 0); \
    } while (0)

// one 64-j sub-chunk: load V (8x16B) + si (4x16B), then 2 KSTEPs
#define SUB(SC, S) do {                                                       \
        const short* vp = vwave + (size_t)(((SC) * 32 + (S) * 8) << 9);       \
        bf16x8 v00 = *(const bf16x8*)(vp);                                    \
        bf16x8 v01 = *(const bf16x8*)(vp + 128);                              \
        bf16x8 v02 = *(const bf16x8*)(vp + 256);                              \
        bf16x8 v03 = *(const bf16x8*)(vp + 384);                              \
        bf16x8 v10 = *(const bf16x8*)(vp + 2048);                             \
        bf16x8 v11 = *(const bf16x8*)(vp + 2048 + 128);                       \
        bf16x8 v12 = *(const bf16x8*)(vp + 2048 + 256);                       \
        bf16x8 v13 = *(const bf16x8*)(vp + 2048 + 384);                       \
        const float* sip = sirow + (SC) * 256 + (S) * 64;                     \
        f32x4 q00 = *(const f32x4*)(sip);                                     \
        f32x4 q01 = *(const f32x4*)(sip + 4);                                 \
        f32x4 q10 = *(const f32x4*)(sip + 32);                                \
        f32x4 q11 = *(const f32x4*)(sip + 36);                                \
        KSTEP(S, 0, q00, q01, v00, v01, v02, v03);                            \
        KSTEP(S, 1, q10, q11, v10, v11, v12, v13);                            \
    } while (0)

    for (int sc = 0; sc < 8; ++sc) {
        int cur = sc & 1;
        const float* ab = &adj_lds[cur][0];
        // sub 0 first (its V/si loads are issued before the stage below, so
        // the compiler's vmcnt waits for them don't drain the HBM stage)
        SUB(sc, 0);
        if (sc < 7) STAGE(cur ^ 1, sc + 1);
        SUB(sc, 1);
        SUB(sc, 2);
        SUB(sc, 3);
        DRAIN_BARRIER();   // LDS-DMA + all reads complete before buffer swap
    }
#undef SUB
#undef KSTEP
#undef STAGE

    // epilogue: denominator for row (jg*4+reg) is acc4[reg] in every lane of
    // the matching group (all-ones B => every column holds the row sum).
    #pragma unroll
    for (int reg = 0; reg < 4; ++reg) {
        int row = jg * 4 + reg;                  // D row = (lane>>4)*4 + reg
        float rcp = 1.0f / acc4[reg];
        float* orow = out + ((size_t)b * NN + i0 + row) * NHF + h * NP;
        #pragma unroll
        for (int o = 0; o < 4; ++o) {
            float y = acc[o][reg] * rcp + bias_v[o];
            y = (y > 0.f) ? y : (__expf(y) - 1.0f);   // ELU
            orow[o * 16 + r] = y;
        }
    }
}

extern "C" void kernel_launch(void* const* d_in, const int* in_sizes, int n_in,
                              void* d_out, int out_size, void* d_ws, size_t ws_size,
                              hipStream_t stream) {
    const float* x      = (const float*)d_in[0];  // node_feats [B,N,F]
    const float* adj    = (const float*)d_in[1];  // adjacency  [B,N,N]
    // d_in[2] = attn_mask -- NOT read; derived from adj (edge <=> adj != 0)
    const float* W      = (const float*)d_in[3];  // kernels    [H,F,FP]
    const float* biases = (const float*)d_in[4];  // [H,FP]
    const float* a_out  = (const float*)d_in[5];  // [H,FP]
    const float* a_in   = (const float*)d_in[6];  // [H,FP]
    float* out = (float*)d_out;

    char* ws = (char*)d_ws;
    short* featsT = (short*)ws;                                // 8 MB bf16, interleaved
    float* s_out  = (float*)(ws + 8388608);                    // 256 KB
    float* s_in   = (float*)(ws + 8388608 + 262144);           // 256 KB

    gat_scores<<<256, 256, 0, stream>>>(x, W, a_out, a_in, s_out, s_in);
    gat_feats<<<NB * NH * (NN / 64), 256, 0, stream>>>(x, W, featsT);
    gat_attn<<<NB * (NN / 16), 256, 0, stream>>>(adj, featsT, s_out, s_in, biases, out);
}